// Round 6
// baseline (320.302 us; speedup 1.0000x reference)
//
#include <hip/hip_runtime.h>
#include <hip/hip_bf16.h>
#include <cstdint>

#define DIM 128
#define BK_SHIFT 7
#define BK_NODES 128          // nodes per bucket
#define MAX_BUCKETS 1024      // supports N <= 131072
#define CUR_STRIDE 16         // pad bucket cursors: 1 per 64B line
#define ST 4096               // edges per hist/scatter block
#define EPT 16                // edges per thread (ST/256)
#define CH_SHIFT 13           // src chunk = src >> 13  (8192 nodes = 2MB of y per chunk)
#define NCHW 16               // chunk slots per node in LDS (>= 13 used)

typedef float f32x4  __attribute__((ext_vector_type(4)));
typedef short bf16x8 __attribute__((ext_vector_type(8)));   // 8 bf16 in 4 VGPRs

__device__ __forceinline__ unsigned bf16_rne(float f) {
    unsigned u = __float_as_uint(f);
    return (u + 0x7fffu + ((u >> 16) & 1u)) >> 16;   // round-to-nearest-even
}

// ---------------- pass 1: per-block bucket histograms -> partial[bucket][block] ----------------
// No global memset, no global atomics: each block writes its own column.
__global__ __launch_bounds__(256) void hist_partial_kernel(const int* __restrict__ dst,
                                                           int* __restrict__ partial,
                                                           int E, int nbk, int nhb) {
    __shared__ int h[MAX_BUCKETS];
    for (int i = threadIdx.x; i < nbk; i += 256) h[i] = 0;
    __syncthreads();
    int base = blockIdx.x * ST;
    #pragma unroll
    for (int k = 0; k < EPT; ++k) {
        int e = base + k * 256 + threadIdx.x;
        if (e < E) atomicAdd(&h[dst[e] >> BK_SHIFT], 1);
    }
    __syncthreads();
    for (int i = threadIdx.x; i < nbk; i += 256)
        partial[(size_t)i * nhb + blockIdx.x] = h[i];
}

// ---------------- pass 2: sum partials + exclusive scan of bucket counts (single block) ----------------
__global__ __launch_bounds__(MAX_BUCKETS) void bucket_scan_kernel(const int* __restrict__ partial,
                                                                  int* __restrict__ boff,
                                                                  int* __restrict__ bcursor,
                                                                  int* __restrict__ offsets,
                                                                  int nbk, int nhb, int N, int E) {
    __shared__ int s[MAX_BUCKETS];
    int tid = threadIdx.x;
    int c = 0;
    if (tid < nbk) {
        const int* p = partial + (size_t)tid * nhb;
        int k = 0;
        for (; k + 4 <= nhb; k += 4) c += p[k] + p[k + 1] + p[k + 2] + p[k + 3];
        for (; k < nhb; ++k) c += p[k];
    }
    s[tid] = c;
    __syncthreads();
    for (int d = 1; d < MAX_BUCKETS; d <<= 1) {
        int v = (tid >= d) ? s[tid - d] : 0;
        __syncthreads();
        s[tid] += v;
        __syncthreads();
    }
    if (tid < nbk) {
        boff[tid + 1] = s[tid];                    // inclusive -> end offset
        bcursor[tid * CUR_STRIDE] = s[tid] - c;    // exclusive -> start (line-padded)
    }
    if (tid == 0) {
        boff[0] = 0;
        offsets[N] = E;                            // CSR sentinel
    }
}

// ---------------- pass 3: block-aggregated scatter to bucket-major buffer ----------------
__global__ __launch_bounds__(256) void bucket_scatter_kernel(const int* __restrict__ src,
                                                             const int* __restrict__ dst,
                                                             int* __restrict__ bcursor,
                                                             int* __restrict__ bbuf,
                                                             int E, int nbk) {
    __shared__ int h[MAX_BUCKETS];   // count, then base
    for (int i = threadIdx.x; i < nbk; i += 256) h[i] = 0;
    __syncthreads();
    int base = blockIdx.x * ST;
    int bk[EPT], rk[EPT], pk[EPT];
    #pragma unroll
    for (int k = 0; k < EPT; ++k) {
        int e = base + k * 256 + threadIdx.x;
        bk[k] = -1;
        if (e < E) {
            int d = dst[e];
            int b = d >> BK_SHIFT;
            bk[k] = b;
            pk[k] = (src[e] << BK_SHIFT) | (d & (BK_NODES - 1));
            rk[k] = atomicAdd(&h[b], 1);
        }
    }
    __syncthreads();
    for (int i = threadIdx.x; i < nbk; i += 256) {
        int c = h[i];
        h[i] = c ? atomicAdd(&bcursor[i * CUR_STRIDE], c) : 0;
    }
    __syncthreads();
    #pragma unroll
    for (int k = 0; k < EPT; ++k) {
        if (bk[k] >= 0) bbuf[h[bk[k]] + rk[k]] = pk[k];
    }
}

// ---------------- pass 4: per-bucket CSR build, chunk-sorted per-node lists ----------------
// Per (node, src-chunk) segments so agg's in-flight gathers sweep src chunks in phase (L2 locality).
__global__ __launch_bounds__(256) void build_csr_kernel(const int* __restrict__ bbuf,
                                                        const int* __restrict__ boff,
                                                        int* __restrict__ offsets,
                                                        float* __restrict__ dinv,
                                                        int* __restrict__ csr_src,
                                                        int N, int nch) {
    __shared__ int cnt2[BK_NODES * NCHW];   // per (node, chunk) counts
    __shared__ int cur2[BK_NODES * NCHW];   // per (node, chunk) cursors
    __shared__ int cnt[BK_NODES];
    __shared__ int sc[BK_NODES];
    int b = blockIdx.x, tid = threadIdx.x;
    int beg = boff[b], end = boff[b + 1];
    for (int i = tid; i < BK_NODES * NCHW; i += 256) cnt2[i] = 0;
    __syncthreads();
    for (int j = beg + tid; j < end; j += 256) {
        int p = bbuf[j];
        atomicAdd(&cnt2[(p & (BK_NODES - 1)) * NCHW + (p >> (BK_SHIFT + CH_SHIFT))], 1);
    }
    __syncthreads();
    if (tid < BK_NODES) {
        int t = 0;
        #pragma unroll
        for (int ch = 0; ch < NCHW; ++ch) t += cnt2[tid * NCHW + ch];
        cnt[tid] = t;
        sc[tid] = t;
    }
    __syncthreads();
    for (int d = 1; d < BK_NODES; d <<= 1) {
        int v = (tid >= d && tid < BK_NODES) ? sc[tid - d] : 0;
        __syncthreads();
        if (tid < BK_NODES) sc[tid] += v;
        __syncthreads();
    }
    if (tid < BK_NODES) {
        int node = b * BK_NODES + tid;
        int running = beg + sc[tid] - cnt[tid];   // node start
        if (node < N) {
            offsets[node] = running;
            dinv[node] = rsqrtf((float)(cnt[tid] + 1));   // +1 self loop
        }
        #pragma unroll
        for (int ch = 0; ch < NCHW; ++ch) {       // chunk-segment cursors, in order
            cur2[tid * NCHW + ch] = running;
            running += cnt2[tid * NCHW + ch];
        }
    }
    __syncthreads();
    for (int j = beg + tid; j < end; j += 256) {
        int p = bbuf[j];
        int idx = (p & (BK_NODES - 1)) * NCHW + (p >> (BK_SHIFT + CH_SHIFT));
        int pos = atomicAdd(&cur2[idx], 1);
        csr_src[pos] = p >> BK_SHIFT;
    }
}

// ---------------- pass 5 (fused): y = bf16(dinv*x)  +  Wt = bf16(W^T) ----------------
__global__ __launch_bounds__(256) void prescale_wconv_kernel(const float* __restrict__ x,
                                                             const float* __restrict__ dinv,
                                                             ushort* __restrict__ y,
                                                             const float* __restrict__ W,
                                                             ushort* __restrict__ Wt,
                                                             int N, int pb) {
    if ((int)blockIdx.x < pb) {
        int t = blockIdx.x * 256 + threadIdx.x;   // one float4 -> 4 bf16 (8B)
        int total = N * (DIM / 4);
        if (t < total) {
            int row = t >> 5;
            float di = dinv[row];
            float4 v = ((const float4*)x)[t];
            uint2 o;
            o.x = bf16_rne(v.x * di) | (bf16_rne(v.y * di) << 16);
            o.y = bf16_rne(v.z * di) | (bf16_rne(v.w * di) << 16);
            ((uint2*)y)[t] = o;
        }
    } else {
        int idx = (blockIdx.x - pb) * 256 + threadIdx.x;
        if (idx < DIM * DIM) {
            int k = idx >> 7, c = idx & (DIM - 1);
            Wt[c * DIM + k] = (ushort)bf16_rne(W[idx]);
        }
    }
}

// ---------------- pass 6 (fused): aggregate 16 rows -> LDS bf16 tile -> MFMA GEMM + bias + PReLU ----------------
// Gather: wave w aggregates nodes base+4w..base+4w+3 (f32 acc, 2 dims/lane), scales by dinv,
// packs bf16 pairs into LDS tile (row stride 272B -> uniform bank spread for b128 reads).
// GEMM: A frag h[m=lane&15][k=quad*8+j] from LDS; B frag Wt[col][k] from global (L2-hot);
// D: col=lane&15, row=quad*4+reg (layout verified in R5).
__global__ __launch_bounds__(256) void agg_gemm_kernel(const ushort* __restrict__ y,
                                                       const int* __restrict__ csr_src,
                                                       const int* __restrict__ offsets,
                                                       const float* __restrict__ dinv,
                                                       const ushort* __restrict__ Wt,
                                                       const float* __restrict__ bias,
                                                       const float* __restrict__ alpha,
                                                       float* __restrict__ out, int N) {
    __shared__ unsigned htile[16 * 68];           // 16 rows x 272B (128 bf16 + 16B pad)
    const unsigned* y32 = (const unsigned*)y;     // 64 dwords per row
    int lane = threadIdx.x & 63;
    int wv   = threadIdx.x >> 6;
    int base = blockIdx.x * 16;

    for (int i = 0; i < 4; ++i) {
        int node = base + wv * 4 + i;
        unsigned packed = 0;
        if (node < N) {
            int beg = offsets[node];
            int end = offsets[node + 1];
            float di = dinv[node];
            unsigned v = y32[(size_t)node * 64 + lane];   // self term (already dinv-scaled)
            float ax = __uint_as_float(v << 16);
            float ay = __uint_as_float(v & 0xffff0000u);
            int j = beg;
            for (; j + 4 <= end; j += 4) {
                int s0 = csr_src[j + 0], s1 = csr_src[j + 1];
                int s2 = csr_src[j + 2], s3 = csr_src[j + 3];
                unsigned v0 = y32[(size_t)s0 * 64 + lane];
                unsigned v1 = y32[(size_t)s1 * 64 + lane];
                unsigned v2 = y32[(size_t)s2 * 64 + lane];
                unsigned v3 = y32[(size_t)s3 * 64 + lane];
                ax += __uint_as_float(v0 << 16); ay += __uint_as_float(v0 & 0xffff0000u);
                ax += __uint_as_float(v1 << 16); ay += __uint_as_float(v1 & 0xffff0000u);
                ax += __uint_as_float(v2 << 16); ay += __uint_as_float(v2 & 0xffff0000u);
                ax += __uint_as_float(v3 << 16); ay += __uint_as_float(v3 & 0xffff0000u);
            }
            for (; j < end; ++j) {
                unsigned vv = y32[(size_t)csr_src[j] * 64 + lane];
                ax += __uint_as_float(vv << 16); ay += __uint_as_float(vv & 0xffff0000u);
            }
            ax *= di; ay *= di;
            packed = bf16_rne(ax) | (bf16_rne(ay) << 16);
        }
        htile[(wv * 4 + i) * 68 + lane] = packed;
    }
    __syncthreads();

    int r = lane & 15, quad = lane >> 4;
    f32x4 acc0 = (f32x4){0.f, 0.f, 0.f, 0.f};
    f32x4 acc1 = (f32x4){0.f, 0.f, 0.f, 0.f};
    int ct0 = wv * 2, ct1 = wv * 2 + 1;
    const char* hbase = (const char*)htile + r * 272 + quad * 16;
    #pragma unroll
    for (int ks = 0; ks < 4; ++ks) {
        bf16x8 a = *(const bf16x8*)(hbase + ks * 64);
        bf16x8 b0 = *(const bf16x8*)(Wt + (size_t)(ct0 * 16 + r) * DIM + ks * 32 + quad * 8);
        bf16x8 b1 = *(const bf16x8*)(Wt + (size_t)(ct1 * 16 + r) * DIM + ks * 32 + quad * 8);
        acc0 = __builtin_amdgcn_mfma_f32_16x16x32_bf16(a, b0, acc0, 0, 0, 0);
        acc1 = __builtin_amdgcn_mfma_f32_16x16x32_bf16(a, b1, acc1, 0, 0, 0);
    }
    int col0 = ct0 * 16 + r, col1 = ct1 * 16 + r;
    float bb0 = bias[col0], al0 = alpha[col0];
    float bb1 = bias[col1], al1 = alpha[col1];
    #pragma unroll
    for (int reg = 0; reg < 4; ++reg) {
        int grow = base + quad * 4 + reg;
        if (grow < N) {
            float v0 = acc0[reg] + bb0; v0 = v0 > 0.f ? v0 : al0 * v0;
            float v1 = acc1[reg] + bb1; v1 = v1 > 0.f ? v1 : al1 * v1;
            out[(size_t)grow * DIM + col0] = v0;
            out[(size_t)grow * DIM + col1] = v1;
        }
    }
}

extern "C" void kernel_launch(void* const* d_in, const int* in_sizes, int n_in,
                              void* d_out, int out_size, void* d_ws, size_t ws_size,
                              hipStream_t stream) {
    const float* x     = (const float*)d_in[0];
    const int*   ei    = (const int*)d_in[1];
    const float* W     = (const float*)d_in[2];
    const float* b     = (const float*)d_in[3];
    const float* alpha = (const float*)d_in[4];
    float* out = (float*)d_out;

    int N = in_sizes[0] / DIM;
    int E = in_sizes[1] / 2;
    const int* src = ei;
    const int* dst = ei + E;
    int nbk = (N + BK_NODES - 1) >> BK_SHIFT;      // 782 for N=100000
    int nhb = (E + ST - 1) / ST;                   // 391 hist/scatter blocks
    int nch = ((N - 1) >> CH_SHIFT) + 1;           // 13 src chunks

    char* ws = (char*)d_ws;
    size_t off = 0;
    auto alloc = [&](size_t bytes) -> char* {
        char* p = ws + off;
        off += (bytes + 255) & ~(size_t)255;
        return p;
    };
    int*    partial = (int*)alloc((size_t)MAX_BUCKETS * nhb * 4);
    int*    boff    = (int*)alloc((size_t)(MAX_BUCKETS + 1) * 4);
    int*    bcursor = (int*)alloc((size_t)MAX_BUCKETS * CUR_STRIDE * 4);
    int*    offsets = (int*)alloc((size_t)(N + 1) * 4);
    float*  dinv    = (float*)alloc((size_t)N * 4);
    int*    bbuf    = (int*)alloc((size_t)E * 4);
    int*    csr_src = (int*)alloc((size_t)E * 4);
    ushort* y       = (ushort*)alloc((size_t)N * DIM * 2);   // bf16, dinv-scaled
    ushort* Wt      = (ushort*)alloc((size_t)DIM * DIM * 2); // bf16, transposed

    int pb = (N * (DIM / 4) + 255) / 256;          // prescale blocks
    int wb = (DIM * DIM + 255) / 256;              // wconv blocks

    hist_partial_kernel<<<nhb, 256, 0, stream>>>(dst, partial, E, nbk, nhb);
    bucket_scan_kernel<<<1, MAX_BUCKETS, 0, stream>>>(partial, boff, bcursor, offsets, nbk, nhb, N, E);
    bucket_scatter_kernel<<<nhb, 256, 0, stream>>>(src, dst, bcursor, bbuf, E, nbk);
    build_csr_kernel<<<nbk, 256, 0, stream>>>(bbuf, boff, offsets, dinv, csr_src, N, nch);
    prescale_wconv_kernel<<<pb + wb, 256, 0, stream>>>(x, dinv, y, W, Wt, N, pb);
    agg_gemm_kernel<<<(N + 15) / 16, 256, 0, stream>>>(y, csr_src, offsets, dinv, Wt, b, alpha, out, N);
}